// Round 12
// baseline (290.665 us; speedup 1.0000x reference)
//
#include <hip/hip_runtime.h>
#include <hip/hip_bf16.h>

// B=64, T=2048, D=U=128 (fixed shape)
#define DD 128
#define UU 128
#define SEQ_T 2048
#define ROWS 64           // rows per chunk
#define NCHUNK 32         // chunks per batch
#define NBLK 1024         // persistent blocks (= 4/CU x 256 CU, co-resident)

typedef __attribute__((ext_vector_type(8))) short short8;   // 8 bf16
typedef __attribute__((ext_vector_type(4))) float f32x4;    // MFMA C/D

__device__ __forceinline__ unsigned short f2bf(float f) {   // RNE fp32->bf16
  unsigned u = __float_as_uint(f);
  u += 0x7fffu + ((u >> 16) & 1u);
  return (unsigned short)(u >> 16);
}
__device__ __forceinline__ float bf2f(unsigned short s) {
  return __uint_as_float(((unsigned)s) << 16);
}
__device__ __forceinline__ float fast_tanh(float v) {
  float z = __expf(2.0f * v);
  return 1.0f - __fdividef(2.0f, z + 1.0f);
}

// ws layout (bytes)
#define WT_OFF   0         // 32768: bf16 Wsum^T [u][d]
#define BIAS_OFF 32768     // 512:   bias sum
#define MW_OFF   33792     // 8192:  per-chunk max (2048 chunks)
#define LW_OFF   41984     // 8192:  per-chunk expsum
#define CNT_OFF  50176     // 256:   per-batch arrival counters (64)

// One-shot: Wt, bias, zero d_out, zero counters (every call -> replay-safe).
__global__ void prep_kernel(const float* __restrict__ W1w, const float* __restrict__ W1b,
                            const float* __restrict__ W2w, const float* __restrict__ W2b,
                            unsigned short* __restrict__ wt_g, float* __restrict__ bias_g,
                            float* __restrict__ out, int* __restrict__ cnt)
{
  int i = blockIdx.x * 256 + threadIdx.x;   // 16384 = 128*128
  int u = i >> 7, d = i & 127;
  float s = W1w[(size_t)d * UU + u] + W2w[(size_t)d * UU + u];
  wt_g[(size_t)u * DD + d] = f2bf(s);
  if (i < UU) bias_g[i] = W1b[i] + W2b[i];
  if (threadIdx.x < 128) out[(size_t)blockIdx.x * DD + threadIdx.x] = 0.0f;
  if (blockIdx.x == 0 && threadIdx.x < 64) cnt[threadIdx.x] = 0;
}

// Persistent fused kernel: block blk owns chunks {blk, blk+1024}.
// Phase S: scores for both chunks (x staged bf16 into 2 LDS tiles, kept).
// Publish (m,l) + release-add per-batch counter. Spin until batch complete,
// acquire, alpha inline, context from the resident LDS tiles (x read ONCE).
__global__ __launch_bounds__(256, 4)
void fused_persist(const float* __restrict__ x,
                   const unsigned short* __restrict__ wt_g,
                   const float* __restrict__ bias_g,
                   const float* __restrict__ Vw,
                   float* __restrict__ mw, float* __restrict__ lw,
                   int* __restrict__ cnt, float* __restrict__ out)
{
  __shared__ __align__(16) unsigned short xs[2][ROWS * DD];  // 2x16 KB swizzled
  __shared__ __align__(16) float spart[4][ROWS];
  __shared__ __align__(16) float pctx[4][DD];

  const int tid = threadIdx.x;
  const int blk = blockIdx.x;            // 0..1023
  const int w = tid >> 6, l = tid & 63, lx = l & 15, lq = l >> 4;

  // ---- B fragments + V/bias for this wave's 32 u-columns (L2-hit) ----
  short8 Bf[2][4];
  float vs[2], bs[2];
  #pragma unroll
  for (int nf = 0; nf < 2; ++nf) {
    const int u = 32 * w + 16 * nf + lx;
    vs[nf] = Vw[u];
    bs[nf] = bias_g[u];
    #pragma unroll
    for (int kf = 0; kf < 4; ++kf)
      Bf[nf][kf] = *reinterpret_cast<const short8*>(
          wt_g + (size_t)u * DD + 32 * kf + 8 * lq);
  }

  float e_keep[2], m_keep[2];

  // ================= Phase S: scores for both chunks =================
  #pragma unroll
  for (int rep = 0; rep < 2; ++rep) {
    const int c = blk + rep * NBLK;
    const int rowbase = c * ROWS;
    unsigned short* xb = xs[rep];

    // stage x -> bf16 swizzled LDS
    #pragma unroll
    for (int it = 0; it < 4; ++it) {
      int F = tid + 256 * it;            // 1024 granules of 8 elems
      int row = F >> 4, g = F & 15;
      const float* src = x + (size_t)(rowbase + row) * DD + g * 8;
      const float4 v0 = *reinterpret_cast<const float4*>(src);
      const float4 v1 = *reinterpret_cast<const float4*>(src + 4);
      short8 pk;
      pk[0] = (short)f2bf(v0.x); pk[1] = (short)f2bf(v0.y);
      pk[2] = (short)f2bf(v0.z); pk[3] = (short)f2bf(v0.w);
      pk[4] = (short)f2bf(v1.x); pk[5] = (short)f2bf(v1.y);
      pk[6] = (short)f2bf(v1.z); pk[7] = (short)f2bf(v1.w);
      *reinterpret_cast<short8*>(xb + row * DD + ((g ^ (row & 15)) << 3)) = pk;
    }
    __syncthreads();   // xs[rep] ready (also orders spart reuse across reps)

    // GEMM: 64 rows x wave's 32 u
    f32x4 acc[4][2];
    #pragma unroll
    for (int mf = 0; mf < 4; ++mf) {
      acc[mf][0] = (f32x4){0.f, 0.f, 0.f, 0.f};
      acc[mf][1] = (f32x4){0.f, 0.f, 0.f, 0.f};
    }
    #pragma unroll
    for (int kf = 0; kf < 4; ++kf) {
      const int gs8 = ((4 * kf + lq) ^ lx) << 3;   // swizzle key: row&15 == lx
      #pragma unroll
      for (int mf = 0; mf < 4; ++mf) {
        short8 a = *reinterpret_cast<const short8*>(xb + (16 * mf + lx) * DD + gs8);
        acc[mf][0] = __builtin_amdgcn_mfma_f32_16x16x32_bf16(a, Bf[0][kf], acc[mf][0], 0, 0, 0);
        acc[mf][1] = __builtin_amdgcn_mfma_f32_16x16x32_bf16(a, Bf[1][kf], acc[mf][1], 0, 0, 0);
      }
    }

    // per-wave score partials
    #pragma unroll
    for (int mf = 0; mf < 4; ++mf) {
      #pragma unroll
      for (int r = 0; r < 4; ++r) {
        float p = vs[0] * fast_tanh(acc[mf][0][r] + bs[0])
                + vs[1] * fast_tanh(acc[mf][1][r] + bs[1]);
        p += __shfl_xor(p, 1);
        p += __shfl_xor(p, 2);
        p += __shfl_xor(p, 4);
        p += __shfl_xor(p, 8);
        if (lx == 0) spart[w][16 * mf + 4 * lq + r] = p;
      }
    }
    __syncthreads();

    // chunk softmax stats (row = lane; every wave holds all 64 rows)
    float sv = (spart[0][l] + spart[1][l]) + (spart[2][l] + spart[3][l]);
    float m = sv;
    #pragma unroll
    for (int off = 1; off < 64; off <<= 1) m = fmaxf(m, __shfl_xor(m, off));
    float e = __expf(sv - m);
    float lsum = e;
    #pragma unroll
    for (int off = 1; off < 64; off <<= 1) lsum += __shfl_xor(lsum, off);

    e_keep[rep] = e;
    m_keep[rep] = m;
    if (tid == 0) { mw[c] = m; lw[c] = lsum; }
  }

  // ---- publish: release both batches ----
  __threadfence();
  if (tid == 0) {
    atomicAdd(&cnt[blk >> 5], 1);                 // batch of chunk blk
    atomicAdd(&cnt[(blk + NBLK) >> 5], 1);        // batch of chunk blk+1024
  }

  // ================= Phase C: context from resident tiles =================
  #pragma unroll
  for (int rep = 0; rep < 2; ++rep) {
    const int c = blk + rep * NBLK;
    const int b = c >> 5;                // batch
    const unsigned short* xb = xs[rep];

    if (tid == 0) {
      while (atomicAdd(&cnt[b], 0) < NCHUNK) __builtin_amdgcn_s_sleep(8);
    }
    __syncthreads();     // all threads wait for arrival (also orders pctx reuse)
    __threadfence();     // acquire: invalidate stale L2 before reading mw/lw

    // inline alpha: combine this batch's 32 (m,l)
    float mi = mw[b * NCHUNK + (l & 31)];
    float li = lw[b * NCHUNK + (l & 31)];
    float M = mi;
    #pragma unroll
    for (int off = 1; off < 32; off <<= 1) M = fmaxf(M, __shfl_xor(M, off));
    float term = __expf(mi - M) * li;
    float L = term;
    #pragma unroll
    for (int off = 1; off < 32; off <<= 1) L += __shfl_xor(L, off);
    const float alpha = __fdividef(__expf(m_keep[rep] - M), L);

    // context from LDS tile; wave w covers rows [16w, 16w+16)
    const int gd = l & 15;
    float ca[8];
    #pragma unroll
    for (int e2 = 0; e2 < 8; ++e2) ca[e2] = 0.0f;
    #pragma unroll
    for (int k = 0; k < 4; ++k) {
      const int row = 16 * w + 4 * (l >> 4) + k;
      const float wgt = alpha * __shfl(e_keep[rep], row);
      short8 xv = *reinterpret_cast<const short8*>(
          xb + row * DD + ((gd ^ (row & 15)) << 3));
      #pragma unroll
      for (int e2 = 0; e2 < 8; ++e2)
        ca[e2] = fmaf(wgt, bf2f((unsigned short)xv[e2]), ca[e2]);
    }
    #pragma unroll
    for (int e2 = 0; e2 < 8; ++e2) {
      ca[e2] += __shfl_xor(ca[e2], 16);
      ca[e2] += __shfl_xor(ca[e2], 32);
    }
    if (l < 16) {        // gd == l
      #pragma unroll
      for (int e2 = 0; e2 < 8; ++e2) pctx[w][l * 8 + e2] = ca[e2];
    }
    __syncthreads();

    if (tid < 128) {
      float c0 = (pctx[0][tid] + pctx[1][tid]) + (pctx[2][tid] + pctx[3][tid]);
      atomicAdd(&out[(size_t)b * DD + tid], c0);
    }
  }
}

extern "C" void kernel_launch(void* const* d_in, const int* in_sizes, int n_in,
                              void* d_out, int out_size, void* d_ws, size_t ws_size,
                              hipStream_t stream)
{
  const float* x   = (const float*)d_in[0];
  const float* W1w = (const float*)d_in[1];
  const float* W1b = (const float*)d_in[2];
  const float* W2w = (const float*)d_in[3];
  const float* W2b = (const float*)d_in[4];
  const float* Vw  = (const float*)d_in[5];
  // d_in[6] = V_b: constant on scores, cancels in softmax.

  char* ws = (char*)d_ws;
  unsigned short* wt_g = (unsigned short*)(ws + WT_OFF);
  float* bias_g = (float*)(ws + BIAS_OFF);
  float* mw  = (float*)(ws + MW_OFF);
  float* lw  = (float*)(ws + LW_OFF);
  int*   cnt = (int*)(ws + CNT_OFF);
  float* out = (float*)d_out;

  prep_kernel<<<64, 256, 0, stream>>>(W1w, W1b, W2w, W2b, wt_g, bias_g, out, cnt);
  fused_persist<<<NBLK, 256, 0, stream>>>(x, wt_g, bias_g, Vw, mw, lw, cnt, out);
}

// Round 13
// 40.139 us; speedup vs baseline: 7.2415x; 7.2415x over previous
//
#include <hip/hip_runtime.h>
#include <hip/hip_bf16.h>

// B=64, T=2048, D=U=128 (fixed shape)
#define DD 128
#define UU 128
#define SEQ_T 2048
#define ROWS 64           // rows per score-chunk
#define NCHUNK 32         // chunks per batch (SEQ_T/ROWS)

typedef __attribute__((ext_vector_type(8))) short short8;   // 8 bf16
typedef __attribute__((ext_vector_type(4))) float f32x4;    // MFMA C/D

__device__ __forceinline__ unsigned short f2bf(float f) {   // HW RNE cvt
  return __builtin_bit_cast(unsigned short, __float2bfloat16(f));
}
__device__ __forceinline__ float bf2f(unsigned short s) {
  return __uint_as_float(((unsigned)s) << 16);
}
__device__ __forceinline__ float fast_tanh(float v) {
  float z = __expf(2.0f * v);
  return 1.0f - __fdividef(2.0f, z + 1.0f);
}

// ws layout (bytes)
#define WT_OFF   0          // 32768: bf16 Wsum^T [u][d]
#define BIAS_OFF 32768      // 512:   bias sum
#define MW_OFF   33792      // 8192:  per-chunk max
#define LW_OFF   41984      // 8192:  per-chunk expsum
#define EW_OFF   50176      // 524288: per-chunk e[64]
#define XBF_OFF  1048576    // 33554432: bf16 copy of x (written by K1)

// One-shot: Wt[u][d] = bf16(W1[d][u]+W2[d][u]); bias; zero d_out (K3 atomics).
__global__ void prep_kernel(const float* __restrict__ W1w, const float* __restrict__ W1b,
                            const float* __restrict__ W2w, const float* __restrict__ W2b,
                            unsigned short* __restrict__ wt_g, float* __restrict__ bias_g,
                            float* __restrict__ out)
{
  int i = blockIdx.x * 256 + threadIdx.x;   // 16384 = 128*128
  int u = i >> 7, d = i & 127;
  float s = W1w[(size_t)d * UU + u] + W2w[(size_t)d * UU + u];
  wt_g[(size_t)u * DD + d] = f2bf(s);
  if (i < UU) bias_g[i] = W1b[i] + W2b[i];
  if (threadIdx.x < 128) out[(size_t)blockIdx.x * DD + threadIdx.x] = 0.0f;  // 64x128
}

// K1: scores. 64 rows/block; stage x->LDS (swizzled bf16) AND publish the
// bf16 tile to ws (linear, coalesced, fire-and-forget) so K3 reads half the
// bytes. MFMA GEMM, tanh+V dot, chunk softmax stats -> {m, l, e[64]}.
__global__ __launch_bounds__(256, 4)
void scores_kernel(const float* __restrict__ x,
                   const unsigned short* __restrict__ wt_g,
                   const float* __restrict__ bias_g,
                   const float* __restrict__ Vw,
                   unsigned short* __restrict__ xbf,
                   float* __restrict__ mw, float* __restrict__ lw,
                   float* __restrict__ e_ws)
{
  __shared__ __align__(16) unsigned short xs[ROWS * DD];  // 16 KB swizzled bf16
  __shared__ __align__(16) float spart[4][ROWS];          // per-wave score partials

  const int tid = threadIdx.x;
  const int blk = blockIdx.x;
  const int rowbase = blk * ROWS;
  const int w = tid >> 6, l = tid & 63, lx = l & 15, lq = l >> 4;

  // ---- stage x: issue HBM/L3 loads first ----
  float4 xr[8];
  #pragma unroll
  for (int it = 0; it < 4; ++it) {
    int F = tid + 256 * it;            // 1024 granules of 8 elems
    int row = F >> 4, g = F & 15;
    const float* src = x + (size_t)(rowbase + row) * DD + g * 8;
    xr[2 * it]     = *reinterpret_cast<const float4*>(src);
    xr[2 * it + 1] = *reinterpret_cast<const float4*>(src + 4);
  }

  // ---- B fragments + V/bias for this wave's 32 u-columns (L2-hit) ----
  short8 Bf[2][4];
  float vs[2], bs[2];
  #pragma unroll
  for (int nf = 0; nf < 2; ++nf) {
    const int u = 32 * w + 16 * nf + lx;
    vs[nf] = Vw[u];
    bs[nf] = bias_g[u];
    #pragma unroll
    for (int kf = 0; kf < 4; ++kf)
      Bf[nf][kf] = *reinterpret_cast<const short8*>(
          wt_g + (size_t)u * DD + 32 * kf + 8 * lq);
  }

  // ---- cvt (HW) + swizzled LDS write + linear global publish ----
  unsigned short* xbf_base = xbf + (size_t)rowbase * DD;
  #pragma unroll
  for (int it = 0; it < 4; ++it) {
    int F = tid + 256 * it;
    int row = F >> 4, g = F & 15;
    float4 v0 = xr[2 * it], v1 = xr[2 * it + 1];
    short8 pk;
    pk[0] = (short)f2bf(v0.x); pk[1] = (short)f2bf(v0.y);
    pk[2] = (short)f2bf(v0.z); pk[3] = (short)f2bf(v0.w);
    pk[4] = (short)f2bf(v1.x); pk[5] = (short)f2bf(v1.y);
    pk[6] = (short)f2bf(v1.z); pk[7] = (short)f2bf(v1.w);
    *reinterpret_cast<short8*>(xs + row * DD + ((g ^ (row & 15)) << 3)) = pk;
    *reinterpret_cast<short8*>(xbf_base + (size_t)F * 8) = pk;   // coalesced
  }
  __syncthreads();

  // ---- GEMM: 64 rows x wave's 32 u; A from LDS, B from regs ----
  f32x4 acc[4][2];
  #pragma unroll
  for (int mf = 0; mf < 4; ++mf) {
    acc[mf][0] = (f32x4){0.f, 0.f, 0.f, 0.f};
    acc[mf][1] = (f32x4){0.f, 0.f, 0.f, 0.f};
  }
  #pragma unroll
  for (int kf = 0; kf < 4; ++kf) {
    const int gs8 = ((4 * kf + lq) ^ lx) << 3;   // swizzle key: row&15 == lx
    #pragma unroll
    for (int mf = 0; mf < 4; ++mf) {
      short8 a = *reinterpret_cast<const short8*>(xs + (16 * mf + lx) * DD + gs8);
      acc[mf][0] = __builtin_amdgcn_mfma_f32_16x16x32_bf16(a, Bf[0][kf], acc[mf][0], 0, 0, 0);
      acc[mf][1] = __builtin_amdgcn_mfma_f32_16x16x32_bf16(a, Bf[1][kf], acc[mf][1], 0, 0, 0);
    }
  }

  // ---- per-wave score partials over this wave's u ----
  #pragma unroll
  for (int mf = 0; mf < 4; ++mf) {
    #pragma unroll
    for (int r = 0; r < 4; ++r) {
      float p = vs[0] * fast_tanh(acc[mf][0][r] + bs[0])
              + vs[1] * fast_tanh(acc[mf][1][r] + bs[1]);
      p += __shfl_xor(p, 1);
      p += __shfl_xor(p, 2);
      p += __shfl_xor(p, 4);
      p += __shfl_xor(p, 8);
      if (lx == 0) spart[w][16 * mf + 4 * lq + r] = p;   // C/D row = 4lq+r
    }
  }
  __syncthreads();

  // ---- chunk softmax stats: row = lane ----
  float sv = (spart[0][l] + spart[1][l]) + (spart[2][l] + spart[3][l]);
  float m = sv;
  #pragma unroll
  for (int off = 1; off < 64; off <<= 1) m = fmaxf(m, __shfl_xor(m, off));
  float e = __expf(sv - m);
  float lsum = e;
  #pragma unroll
  for (int off = 1; off < 64; off <<= 1) lsum += __shfl_xor(lsum, off);

  if (w == 0) e_ws[(size_t)blk * ROWS + l] = e;
  if (tid == 0) { mw[blk] = m; lw[blk] = lsum; }
}

// K3: context from the bf16 tile (half the read traffic), alpha inlined.
__global__ __launch_bounds__(256, 8)
void context_kernel(const unsigned short* __restrict__ xbf,
                    const float* __restrict__ mw, const float* __restrict__ lw,
                    const float* __restrict__ e_ws,
                    float* __restrict__ out)
{
  __shared__ __align__(16) float pctx[4][DD];

  const int tid = threadIdx.x;
  const int blk = blockIdx.x;          // 2048
  const int rowbase = blk * ROWS;
  const int b = blk >> 5;              // batch
  const int c = blk & 31;              // chunk
  const int w = tid >> 6, l = tid & 63;
  const int gd = tid & 15;             // d-granule (8 elems)
  const int tg = tid >> 4;             // 16 groups of 4 rows

  // ---- inline alpha: global softmax combine over this batch's 32 chunks ----
  float mi = mw[b * NCHUNK + (l & 31)];
  float li = lw[b * NCHUNK + (l & 31)];
  float M = mi;
  #pragma unroll
  for (int off = 1; off < 32; off <<= 1) M = fmaxf(M, __shfl_xor(M, off));
  float term = __expf(mi - M) * li;
  float L = term;
  #pragma unroll
  for (int off = 1; off < 32; off <<= 1) L += __shfl_xor(L, off);
  const float mc = __shfl(mi, c & 31);            // this chunk's max
  const float alpha = __fdividef(__expf(mc - M), L);

  float ca[8];
  #pragma unroll
  for (int e2 = 0; e2 < 8; ++e2) ca[e2] = 0.0f;
  #pragma unroll
  for (int k = 0; k < 4; ++k) {
    const int row = tg * 4 + k;
    const float wgt = alpha * e_ws[(size_t)blk * ROWS + row];
    short8 xv = *reinterpret_cast<const short8*>(
        xbf + (size_t)(rowbase + row) * DD + gd * 8);
    #pragma unroll
    for (int e2 = 0; e2 < 8; ++e2)
      ca[e2] = fmaf(wgt, bf2f((unsigned short)xv[e2]), ca[e2]);
  }
  #pragma unroll
  for (int e2 = 0; e2 < 8; ++e2) {
    ca[e2] += __shfl_xor(ca[e2], 16);
    ca[e2] += __shfl_xor(ca[e2], 32);
  }
  if (l < 16) {     // gd == l for these lanes
    #pragma unroll
    for (int e2 = 0; e2 < 8; ++e2) pctx[w][l * 8 + e2] = ca[e2];
  }
  __syncthreads();

  if (tid < 128) {
    float c0 = (pctx[0][tid] + pctx[1][tid]) + (pctx[2][tid] + pctx[3][tid]);
    atomicAdd(&out[(size_t)b * DD + tid], c0);
  }
}

extern "C" void kernel_launch(void* const* d_in, const int* in_sizes, int n_in,
                              void* d_out, int out_size, void* d_ws, size_t ws_size,
                              hipStream_t stream)
{
  const float* x   = (const float*)d_in[0];
  const float* W1w = (const float*)d_in[1];
  const float* W1b = (const float*)d_in[2];
  const float* W2w = (const float*)d_in[3];
  const float* W2b = (const float*)d_in[4];
  const float* Vw  = (const float*)d_in[5];
  // d_in[6] = V_b: constant on scores, cancels in softmax.

  const int bt = in_sizes[0] / DD;       // 131072
  const int nblk = bt / ROWS;            // 2048

  char* ws = (char*)d_ws;
  unsigned short* wt_g = (unsigned short*)(ws + WT_OFF);
  float* bias_g = (float*)(ws + BIAS_OFF);
  float* mw   = (float*)(ws + MW_OFF);
  float* lw   = (float*)(ws + LW_OFF);
  float* e_ws = (float*)(ws + EW_OFF);
  unsigned short* xbf = (unsigned short*)(ws + XBF_OFF);
  float* out  = (float*)d_out;

  prep_kernel<<<64, 256, 0, stream>>>(W1w, W1b, W2w, W2b, wt_g, bias_g, out);
  scores_kernel<<<nblk, 256, 0, stream>>>(x, wt_g, bias_g, Vw, xbf, mw, lw, e_ws);
  context_kernel<<<nblk, 256, 0, stream>>>(xbf, mw, lw, e_ws, out);
}

// Round 14
// 38.314 us; speedup vs baseline: 7.5865x; 1.0476x over previous
//
#include <hip/hip_runtime.h>
#include <hip/hip_bf16.h>

// B=64, T=2048, D=U=128 (fixed shape)
#define DD 128
#define UU 128
#define SEQ_T 2048
#define ROWS 64           // rows per score-chunk
#define NCHUNK 32         // chunks per batch (SEQ_T/ROWS)

typedef __attribute__((ext_vector_type(8))) short short8;   // 8 bf16
typedef __attribute__((ext_vector_type(4))) float f32x4;    // MFMA C/D

__device__ __forceinline__ unsigned short f2bf(float f) {   // HW RNE cvt
  return __builtin_bit_cast(unsigned short, __float2bfloat16(f));
}
__device__ __forceinline__ float bf2f(unsigned short s) {
  return __uint_as_float(((unsigned)s) << 16);
}
__device__ __forceinline__ float fast_tanh(float v) {
  float z = __expf(2.0f * v);
  return 1.0f - __fdividef(2.0f, z + 1.0f);
}

// ws layout (bytes)
#define WT_OFF   0          // 32768: bf16 Wsum^T [u][d]
#define BIAS_OFF 32768      // 512:   bias sum
#define MW_OFF   33792      // 8192:  per-chunk max
#define LW_OFF   41984      // 8192:  per-chunk expsum
#define EW_OFF   50176      // 524288: per-chunk e[64]

// One-shot: Wt[u][d] = bf16(W1[d][u]+W2[d][u]); bias; zero d_out (K3 atomics).
__global__ void prep_kernel(const float* __restrict__ W1w, const float* __restrict__ W1b,
                            const float* __restrict__ W2w, const float* __restrict__ W2b,
                            unsigned short* __restrict__ wt_g, float* __restrict__ bias_g,
                            float* __restrict__ out)
{
  int i = blockIdx.x * 256 + threadIdx.x;   // 16384 = 128*128
  int u = i >> 7, d = i & 127;
  float s = W1w[(size_t)d * UU + u] + W2w[(size_t)d * UU + u];
  wt_g[(size_t)u * DD + d] = f2bf(s);
  if (i < UU) bias_g[i] = W1b[i] + W2b[i];
  if (threadIdx.x < 128) out[(size_t)blockIdx.x * DD + threadIdx.x] = 0.0f;  // 64x128
}

// K1: scores with SWAPPED MFMA operands: C[u][x-row] so the V.tanh dot over
// u is lane-local (32 in-lane fma + 2 shfl) -- no per-(mf,r) shuffle trees,
// no spart round-trip. wt staged in LDS (each wave needs all 128 u).
__global__ __launch_bounds__(256, 3)
void scores_kernel(const float* __restrict__ x,
                   const unsigned short* __restrict__ wt_g,
                   const float* __restrict__ bias_g,
                   const float* __restrict__ Vw,
                   float* __restrict__ mw, float* __restrict__ lw,
                   float* __restrict__ e_ws)
{
  __shared__ __align__(16) unsigned short xs[ROWS * DD];   // 16 KB swizzled bf16
  __shared__ __align__(16) unsigned short wtl[UU * DD];    // 32 KB swizzled bf16
  __shared__ __align__(16) float bsum[UU];
  __shared__ __align__(16) float vv[UU];
  __shared__ float slds[ROWS];

  const int tid = threadIdx.x;
  const int blk = blockIdx.x;
  const int rowbase = blk * ROWS;
  const int w = tid >> 6, l = tid & 63, lx = l & 15, lq = l >> 4;

  // ---- stage x: issue HBM/L3 loads first ----
  float4 xr[8];
  #pragma unroll
  for (int it = 0; it < 4; ++it) {
    int F = tid + 256 * it;            // 1024 granules of 8 elems
    int row = F >> 4, g = F & 15;
    const float* src = x + (size_t)(rowbase + row) * DD + g * 8;
    xr[2 * it]     = *reinterpret_cast<const float4*>(src);
    xr[2 * it + 1] = *reinterpret_cast<const float4*>(src + 4);
  }

  // ---- stage wt -> swizzled LDS (L2-hit; r2-verified layout) ----
  #pragma unroll
  for (int it = 0; it < 8; ++it) {
    int F = tid + 256 * it;            // 2048 granules
    int u = F >> 4, g = F & 15;
    short8 wv = *reinterpret_cast<const short8*>(wt_g + (size_t)F * 8);
    *reinterpret_cast<short8*>(wtl + u * DD + ((g ^ (u & 15)) << 3)) = wv;
  }
  if (tid < UU) { bsum[tid] = bias_g[tid]; vv[tid] = Vw[tid]; }

  // ---- cvt x + swizzled LDS write ----
  #pragma unroll
  for (int it = 0; it < 4; ++it) {
    int F = tid + 256 * it;
    int row = F >> 4, g = F & 15;
    float4 v0 = xr[2 * it], v1 = xr[2 * it + 1];
    short8 pk;
    pk[0] = (short)f2bf(v0.x); pk[1] = (short)f2bf(v0.y);
    pk[2] = (short)f2bf(v0.z); pk[3] = (short)f2bf(v0.w);
    pk[4] = (short)f2bf(v1.x); pk[5] = (short)f2bf(v1.y);
    pk[6] = (short)f2bf(v1.z); pk[7] = (short)f2bf(v1.w);
    *reinterpret_cast<short8*>(xs + row * DD + ((g ^ (row & 15)) << 3)) = pk;
  }
  __syncthreads();

  // ---- GEMM (swapped): wave w owns x-rows [16w,16w+16), all 128 u ----
  // B-frag = x-row fragment (col dim = x-row), A-frag = wt row (u dim).
  f32x4 acc[8];
  #pragma unroll
  for (int nf = 0; nf < 8; ++nf) acc[nf] = (f32x4){0.f, 0.f, 0.f, 0.f};
  #pragma unroll
  for (int kf = 0; kf < 4; ++kf) {
    const int gs8 = ((4 * kf + lq) ^ lx) << 3;   // row&15 == lx for both tiles
    short8 bx = *reinterpret_cast<const short8*>(xs + (16 * w + lx) * DD + gs8);
    #pragma unroll
    for (int nf = 0; nf < 8; ++nf) {
      short8 aw = *reinterpret_cast<const short8*>(wtl + (16 * nf + lx) * DD + gs8);
      acc[nf] = __builtin_amdgcn_mfma_f32_16x16x32_bf16(aw, bx, acc[nf], 0, 0, 0);
    }
  }

  // ---- lane-local V-dot: lane holds u = 16nf+4lq+r for x-row 16w+lx ----
  float p = 0.0f;
  #pragma unroll
  for (int nf = 0; nf < 8; ++nf) {
    const f32x4 bs4 = *reinterpret_cast<const f32x4*>(bsum + 16 * nf + 4 * lq);
    const f32x4 vs4 = *reinterpret_cast<const f32x4*>(vv + 16 * nf + 4 * lq);
    #pragma unroll
    for (int r = 0; r < 4; ++r)
      p += vs4[r] * fast_tanh(acc[nf][r] + bs4[r]);
  }
  // complete u-sum across the 4 lq-lanes holding the same x-row
  p += __shfl_xor(p, 16);
  p += __shfl_xor(p, 32);
  if (l < 16) slds[16 * w + l] = p;   // lq==0 lanes publish their row's score
  __syncthreads();

  // ---- chunk softmax stats: row = lane ----
  float sv = slds[l];
  float m = sv;
  #pragma unroll
  for (int off = 1; off < 64; off <<= 1) m = fmaxf(m, __shfl_xor(m, off));
  float e = __expf(sv - m);
  float lsum = e;
  #pragma unroll
  for (int off = 1; off < 64; off <<= 1) lsum += __shfl_xor(lsum, off);

  if (w == 0) e_ws[(size_t)blk * ROWS + l] = e;
  if (tid == 0) { mw[blk] = m; lw[blk] = lsum; }
}

// K3: context (r11-verified): alpha inlined, stream x fp32, atomics to out.
__global__ __launch_bounds__(256, 8)
void context_kernel(const float* __restrict__ x,
                    const float* __restrict__ mw, const float* __restrict__ lw,
                    const float* __restrict__ e_ws,
                    float* __restrict__ out)
{
  __shared__ __align__(16) float pctx[4][DD];

  const int tid = threadIdx.x;
  const int blk = blockIdx.x;          // 2048
  const int rowbase = blk * ROWS;
  const int b = blk >> 5;              // batch
  const int c = blk & 31;              // chunk
  const int w = tid >> 6, l = tid & 63;
  const int gd = tid & 15;             // d-granule (8 floats)
  const int tg = tid >> 4;             // 16 groups of 4 rows

  // ---- inline alpha: global softmax combine over this batch's 32 chunks ----
  float mi = mw[b * NCHUNK + (l & 31)];
  float li = lw[b * NCHUNK + (l & 31)];
  float M = mi;
  #pragma unroll
  for (int off = 1; off < 32; off <<= 1) M = fmaxf(M, __shfl_xor(M, off));
  float term = __expf(mi - M) * li;
  float L = term;
  #pragma unroll
  for (int off = 1; off < 32; off <<= 1) L += __shfl_xor(L, off);
  const float mc = __shfl(mi, c & 31);            // this chunk's max
  const float alpha = __fdividef(__expf(mc - M), L);

  float ca[8];
  #pragma unroll
  for (int e2 = 0; e2 < 8; ++e2) ca[e2] = 0.0f;
  #pragma unroll
  for (int k = 0; k < 4; ++k) {
    const int row = tg * 4 + k;
    const float wgt = alpha * e_ws[(size_t)blk * ROWS + row];
    const float* src = x + (size_t)(rowbase + row) * DD + gd * 8;
    const float4 v0 = *reinterpret_cast<const float4*>(src);
    const float4 v1 = *reinterpret_cast<const float4*>(src + 4);
    ca[0] = fmaf(wgt, v0.x, ca[0]); ca[1] = fmaf(wgt, v0.y, ca[1]);
    ca[2] = fmaf(wgt, v0.z, ca[2]); ca[3] = fmaf(wgt, v0.w, ca[3]);
    ca[4] = fmaf(wgt, v1.x, ca[4]); ca[5] = fmaf(wgt, v1.y, ca[5]);
    ca[6] = fmaf(wgt, v1.z, ca[6]); ca[7] = fmaf(wgt, v1.w, ca[7]);
  }
  #pragma unroll
  for (int e2 = 0; e2 < 8; ++e2) {
    ca[e2] += __shfl_xor(ca[e2], 16);
    ca[e2] += __shfl_xor(ca[e2], 32);
  }
  if (l < 16) {     // gd == l for these lanes
    #pragma unroll
    for (int e2 = 0; e2 < 8; ++e2) pctx[w][l * 8 + e2] = ca[e2];
  }
  __syncthreads();

  if (tid < 128) {
    float c0 = (pctx[0][tid] + pctx[1][tid]) + (pctx[2][tid] + pctx[3][tid]);
    atomicAdd(&out[(size_t)b * DD + tid], c0);
  }
}

extern "C" void kernel_launch(void* const* d_in, const int* in_sizes, int n_in,
                              void* d_out, int out_size, void* d_ws, size_t ws_size,
                              hipStream_t stream)
{
  const float* x   = (const float*)d_in[0];
  const float* W1w = (const float*)d_in[1];
  const float* W1b = (const float*)d_in[2];
  const float* W2w = (const float*)d_in[3];
  const float* W2b = (const float*)d_in[4];
  const float* Vw  = (const float*)d_in[5];
  // d_in[6] = V_b: constant on scores, cancels in softmax.

  const int bt = in_sizes[0] / DD;       // 131072
  const int nblk = bt / ROWS;            // 2048

  char* ws = (char*)d_ws;
  unsigned short* wt_g = (unsigned short*)(ws + WT_OFF);
  float* bias_g = (float*)(ws + BIAS_OFF);
  float* mw   = (float*)(ws + MW_OFF);
  float* lw   = (float*)(ws + LW_OFF);
  float* e_ws = (float*)(ws + EW_OFF);
  float* out  = (float*)d_out;

  prep_kernel<<<64, 256, 0, stream>>>(W1w, W1b, W2w, W2b, wt_g, bias_g, out);
  scores_kernel<<<nblk, 256, 0, stream>>>(x, wt_g, bias_g, Vw, mw, lw, e_ws);
  context_kernel<<<nblk, 256, 0, stream>>>(x, mw, lw, e_ws, out);
}